// Round 4
// baseline (6426.332 us; speedup 1.0000x reference)
//
#include <hip/hip_runtime.h>

#define BB 64
#define TT 2048
#define FF 15
#define UU 256
#define N3 768
#define NP 128          // 128 k-pairs (256 rows) of U per column
#define NQ 32           // k-pairs held per thread (quarter of a column)
#define QP (NQ + 4)     // padded pairs per klo-quarter (+16B): the 4 quarter
                        // base addresses land on disjoint bank quads

typedef _Float16 half2v __attribute__((ext_vector_type(2)));

__device__ float  g_seq1[BB * TT * UU];          // 134 MB
__device__ float  g_xp[(size_t)BB * TT * N3];    // 402 MB (xp1 then xp2)
__device__ half2v g_U1h[NP * N3];
__device__ half2v g_U2h[NP * N3];

__device__ __forceinline__ float dot2f(half2v a, half2v b, float c) {
#if __has_builtin(__builtin_amdgcn_fdot2)
    return __builtin_amdgcn_fdot2(a, b, c, false);
#else
    return c + (float)a.x * (float)b.x + (float)a.y * (float)b.y;
#endif
}

// Pack U (fp32 [256][768]) into k-pair f16 layout: Uh[p*768+j] = {U[2p][j], U[2p+1][j]}
__global__ __launch_bounds__(256) void prep_uh(const float* __restrict__ U,
                                               half2v* __restrict__ Uh) {
    int idx = blockIdx.x * 256 + threadIdx.x;    // 0 .. 128*768-1
    int p = idx / N3, j = idx - p * N3;
    half2v v;
    v.x = (_Float16)U[(2 * p + 0) * N3 + j];
    v.y = (_Float16)U[(2 * p + 1) * N3 + j];
    Uh[idx] = v;
}

// xp1 = x @ W1 + b_in   (K=15, memory-bound)
__global__ __launch_bounds__(256) void gemm_k15(
    const float* __restrict__ x, const float* __restrict__ W1,
    const float* __restrict__ bin, float* __restrict__ C) {
    __shared__ float xr[8][FF];
    const int m0 = blockIdx.x * 8;
    const int j  = blockIdx.y * 256 + threadIdx.x;
    if (threadIdx.x < 8 * FF) {
        int r = threadIdx.x / FF, k = threadIdx.x - r * FF;
        xr[r][k] = x[(size_t)(m0 + r) * FF + k];
    }
    __syncthreads();
    float wv[FF];
#pragma unroll
    for (int k = 0; k < FF; k++) wv[k] = W1[k * N3 + j];
    const float bj = bin[j];
#pragma unroll
    for (int r = 0; r < 8; r++) {
        float a = bj;
#pragma unroll
        for (int k = 0; k < FF; k++) a += xr[r][k] * wv[k];
        C[(size_t)(m0 + r) * N3 + j] = a;
    }
}

// xp2 = seq1 @ W2 + b_in   (M=131072, N=768, K=256) tiled fp32 GEMM
__global__ __launch_bounds__(256) void gemm_xp(
    const float* __restrict__ A, const float* __restrict__ Bw,
    const float* __restrict__ bin, float* __restrict__ C) {
    __shared__ float As[16][64];
    __shared__ float Bs[16][64];
    const int tid = threadIdx.x;
    const int m0 = blockIdx.x * 64, n0 = blockIdx.y * 64;
    const int tm = (tid & 15) * 4;
    const int tn = (tid >> 4) * 4;
    float acc[4][4] = {};
    const int lm = tid >> 2, lk = (tid & 3) * 4;
    const int lkb = tid >> 4, ln = (tid & 15) * 4;
    for (int k0 = 0; k0 < 256; k0 += 16) {
        float4 av = *(const float4*)&A[(size_t)(m0 + lm) * 256 + k0 + lk];
        float4 bv = *(const float4*)&Bw[(size_t)(k0 + lkb) * N3 + n0 + ln];
        As[lk + 0][lm] = av.x; As[lk + 1][lm] = av.y;
        As[lk + 2][lm] = av.z; As[lk + 3][lm] = av.w;
        *(float4*)&Bs[lkb][ln] = bv;
        __syncthreads();
#pragma unroll
        for (int kk = 0; kk < 16; kk++) {
            float4 a = *(const float4*)&As[kk][tm];
            float4 b = *(const float4*)&Bs[kk][tn];
            acc[0][0] += a.x * b.x; acc[0][1] += a.x * b.y; acc[0][2] += a.x * b.z; acc[0][3] += a.x * b.w;
            acc[1][0] += a.y * b.x; acc[1][1] += a.y * b.y; acc[1][2] += a.y * b.z; acc[1][3] += a.y * b.w;
            acc[2][0] += a.z * b.x; acc[2][1] += a.z * b.y; acc[2][2] += a.z * b.z; acc[2][3] += a.z * b.w;
            acc[3][0] += a.w * b.x; acc[3][1] += a.w * b.y; acc[3][2] += a.w * b.z; acc[3][3] += a.w * b.w;
        }
        __syncthreads();
    }
#pragma unroll
    for (int i = 0; i < 4; i++) {
        float4 o = make_float4(acc[i][0] + bin[n0 + tn + 0], acc[i][1] + bin[n0 + tn + 1],
                               acc[i][2] + bin[n0 + tn + 2], acc[i][3] + bin[n0 + tn + 3]);
        *(float4*)&C[(size_t)(m0 + tm + i) * N3 + n0 + tn] = o;
    }
}

#define U0(Q) __builtin_bit_cast(half2v, u0[(Q)])
#define U1(Q) __builtin_bit_cast(half2v, u1[(Q)])
#define U2(Q) __builtin_bit_cast(half2v, u2[(Q)])

// 12 dot2s fed by one float4 (4 h-pairs) of broadcast h
#define DOT4PAIRS(HV, Q)                                     \
    {                                                        \
        half2v* hp_ = (half2v*)&(HV);                        \
        a0a = dot2f(hp_[0], U0((Q) + 0), a0a);               \
        a1a = dot2f(hp_[0], U1((Q) + 0), a1a);               \
        a2a = dot2f(hp_[0], U2((Q) + 0), a2a);               \
        a0b = dot2f(hp_[1], U0((Q) + 1), a0b);               \
        a1b = dot2f(hp_[1], U1((Q) + 1), a1b);               \
        a2b = dot2f(hp_[1], U2((Q) + 1), a2b);               \
        a0a = dot2f(hp_[2], U0((Q) + 2), a0a);               \
        a1a = dot2f(hp_[2], U1((Q) + 2), a1a);               \
        a2a = dot2f(hp_[2], U2((Q) + 2), a2a);               \
        a0b = dot2f(hp_[3], U0((Q) + 3), a0b);               \
        a1b = dot2f(hp_[3], U1((Q) + 3), a1b);               \
        a2b = dot2f(hp_[3], U2((Q) + 3), a2b);               \
    }

// GRU recurrence, one WG per batch element. 1024 threads; threads 4u..4u+3
// co-own unit u: each holds a QUARTER of the k-range (32 f16-pairs) of all
// three gate columns => 96 U-VGPRs/thread + ~25 overhead ~= 121, which fits
// under the 128-VGPR cap that 1024-thread blocks impose. Rounds 2-3 proved
// the allocator refuses to hold 192 U-regs (it spilled to AGPRs and paid a
// full v_accvgpr_read pass per step, ~1300 cyc); at 96 regs there is no
// cheaper alternative than keeping them resident.
__global__ __launch_bounds__(1024) __attribute__((amdgpu_waves_per_eu(4, 4)))
void gru_recur4(
    const half2v* __restrict__ Uh, const float* __restrict__ brec,
    const float* __restrict__ xp, float* __restrict__ seq_out,
    float* __restrict__ state_out, float* __restrict__ extra_out) {
    const int b = blockIdx.x, j = threadIdx.x;     // j in [0,1024)
    const int u   = j >> 2;                        // unit index 0..255
    const int klo = j & 3;                         // k-quarter 0..3

    // packed h (f16 pairs), double-buffered; quarters padded apart by 16B
    __shared__ __align__(16) half2v h2s[2][4 * QP];

    // load this thread's quarter of the three U columns into VGPRs
    unsigned int u0[NQ], u1[NQ], u2[NQ];
    const unsigned int* Uw = (const unsigned int*)Uh;
#pragma unroll
    for (int q = 0; q < NQ; q++) {
        int row = klo * NQ + q;
        u0[q] = Uw[row * N3 + u];
        u1[q] = Uw[row * N3 + u + UU];
        u2[q] = Uw[row * N3 + u + 2 * UU];
    }
#pragma unroll
    for (int q = 0; q < NQ; q++) {
        asm volatile("" : "+v"(u0[q]), "+v"(u1[q]), "+v"(u2[q]));
    }
    const float br0 = brec[u], br1 = brec[u + UU], br2 = brec[u + 2 * UU];

    if (j < 4 * QP) { half2v z0; z0.x = (_Float16)0.f; z0.y = (_Float16)0.f; h2s[0][j] = z0; }
    float hst = 0.f;                               // fp32 h state, in-register
    __syncthreads();

    const float* __restrict__ xpb = xp + (size_t)b * TT * N3;
    float xz = xpb[u], xr = xpb[u + UU], xh = xpb[u + 2 * UU];

    for (int t = 0; t < TT; t++) {
        // prefetch next step's x-projection
        const float* xn = xpb + (size_t)(t + 1 < TT ? t + 1 : t) * N3;
        float xzn = xn[u], xrn = xn[u + UU], xhn = xn[u + 2 * UU];

        // partial rec_g = sum_{k in my quarter} h[k] * U[k][col_g]
        float a0a = 0.f, a0b = 0.f, a1a = 0.f, a1b = 0.f, a2a = 0.f, a2b = 0.f;
        const float4* hb4 = (const float4*)h2s[t & 1] + 9 * klo;  // QP/4 = 9
#pragma unroll
        for (int p4 = 0; p4 < NQ / 4; p4++) {
            float4 hv = hb4[p4];
            DOT4PAIRS(hv, 4 * p4);
        }
        // combine the 4 k-quarters (lanes j^1, j^2 within the wave)
        float az = a0a + a0b; az += __shfl_xor(az, 1); az += __shfl_xor(az, 2);
        float ar = a1a + a1b; ar += __shfl_xor(ar, 1); ar += __shfl_xor(ar, 2);
        float ah = a2a + a2b; ah += __shfl_xor(ah, 1); ah += __shfl_xor(ah, 2);

        // gates (computed redundantly on all 4 partners; all thread-local)
        float z  = 1.f / (1.f + __expf(-(xz + az + br0)));
        float r  = 1.f / (1.f + __expf(-(xr + ar + br1)));
        float hh = xh + r * (ah + br2);
        hh = hh > 0.f ? hh : 0.f;
        float hn = z * hst + (1.f - z) * hh;
        hst = hn;

        // pack h into f16 pairs for next step's broadcast:
        // pair m = {h[2m], h[2m+1]}: owner thread j=8m, partner j=8m+4
        float hq = __shfl_xor(hn, 4);
        if ((j & 7) == 0) {
            int m = j >> 3;
            int slot = m + 4 * (m >> 5);           // skip 16B pad per quarter
            half2v pk; pk.x = (_Float16)hn; pk.y = (_Float16)hq;
            h2s[(t + 1) & 1][slot] = pk;
        }
        if (seq_out && klo == 0)
            seq_out[(size_t)b * TT * UU + (size_t)t * UU + u] = hn;
        __syncthreads();                           // single barrier per step
        xz = xzn; xr = xrn; xh = xhn;
    }

    if (klo == 0) {
        state_out[b * UU + u] = hst;
        if (extra_out) extra_out[b * UU + u] = hst;
    }
}

extern "C" void kernel_launch(void* const* d_in, const int* in_sizes, int n_in,
                              void* d_out, int out_size, void* d_ws, size_t ws_size,
                              hipStream_t stream) {
    const float* x  = (const float*)d_in[0];
    const float* W1 = (const float*)d_in[1];
    const float* U1 = (const float*)d_in[2];
    const float* b1 = (const float*)d_in[3];
    const float* W2 = (const float*)d_in[4];
    const float* U2 = (const float*)d_in[5];
    const float* b2 = (const float*)d_in[6];
    float* out = (float*)d_out;

    half2v* U1h; hipGetSymbolAddress((void**)&U1h, HIP_SYMBOL(g_U1h));
    half2v* U2h; hipGetSymbolAddress((void**)&U2h, HIP_SYMBOL(g_U2h));
    float*  seq1; hipGetSymbolAddress((void**)&seq1, HIP_SYMBOL(g_seq1));
    float*  xp;   hipGetSymbolAddress((void**)&xp,   HIP_SYMBOL(g_xp));

    prep_uh<<<NP * N3 / 256, 256, 0, stream>>>(U1, U1h);
    prep_uh<<<NP * N3 / 256, 256, 0, stream>>>(U2, U2h);

    // layer 1
    gemm_k15<<<dim3(BB * TT / 8, 3), 256, 0, stream>>>(x, W1, b1, xp);
    gru_recur4<<<BB, 1024, 0, stream>>>(U1h, b1 + N3, xp, seq1, out + BB * UU, nullptr);

    // layer 2
    gemm_xp<<<dim3(BB * TT / 64, N3 / 64), 256, 0, stream>>>(seq1, W2, b2, xp);
    gru_recur4<<<BB, 1024, 0, stream>>>(U2h, b2 + N3, xp, nullptr, out + 2 * BB * UU, out);
}

// Round 5
// 5860.153 us; speedup vs baseline: 1.0966x; 1.0966x over previous
//
#include <hip/hip_runtime.h>

#define BB 64
#define TT 2048
#define FF 15
#define UU 256
#define N3 768

typedef _Float16 half8 __attribute__((ext_vector_type(8)));
typedef _Float16 half2v __attribute__((ext_vector_type(2)));
typedef float f32x4 __attribute__((ext_vector_type(4)));

__device__ float g_seq1[BB * TT * UU];          // 134 MB
__device__ float g_xp[(size_t)BB * TT * N3];    // 402 MB (xp1 then xp2)
__device__ uint4 g_U1p[48 * 8 * 64];            // 48 n-tiles x 8 k-tiles x 64 lanes x 16B
__device__ uint4 g_U2p[48 * 8 * 64];

// Pack U (fp32 [256][768]) into per-lane MFMA B-fragments (f16).
// Fragment (nt, kt), lane l, dword d holds {U[kt*32+8*(l>>4)+2d][nt*16+(l&15)],
// U[...+2d+1][...]}. The k-mapping f(l,i)=8*(l>>4)+i is the SAME function used
// when building the A fragment from h in the gru kernel, so any symmetric
// hardware k-permutation cancels.
__global__ __launch_bounds__(256) void prep_upk(const float* __restrict__ U,
                                                unsigned* __restrict__ Up) {
    int idx = blockIdx.x * 256 + threadIdx.x;    // 0 .. 98303
    int d = idx & 3, l = (idx >> 2) & 63, kt = (idx >> 8) & 7, nt = idx >> 11;
    int row = kt * 32 + ((l >> 4) << 3) + 2 * d;
    int col = nt * 16 + (l & 15);
    unsigned short lo = __builtin_bit_cast(unsigned short, (_Float16)U[row * N3 + col]);
    unsigned short hi = __builtin_bit_cast(unsigned short, (_Float16)U[(row + 1) * N3 + col]);
    Up[idx] = (unsigned)lo | ((unsigned)hi << 16);
}

// xp1 = x @ W1 + b_in   (K=15, memory-bound)
__global__ __launch_bounds__(256) void gemm_k15(
    const float* __restrict__ x, const float* __restrict__ W1,
    const float* __restrict__ bin, float* __restrict__ C) {
    __shared__ float xr[8][FF];
    const int m0 = blockIdx.x * 8;
    const int j  = blockIdx.y * 256 + threadIdx.x;
    if (threadIdx.x < 8 * FF) {
        int r = threadIdx.x / FF, k = threadIdx.x - r * FF;
        xr[r][k] = x[(size_t)(m0 + r) * FF + k];
    }
    __syncthreads();
    float wv[FF];
#pragma unroll
    for (int k = 0; k < FF; k++) wv[k] = W1[k * N3 + j];
    const float bj = bin[j];
#pragma unroll
    for (int r = 0; r < 8; r++) {
        float a = bj;
#pragma unroll
        for (int k = 0; k < FF; k++) a += xr[r][k] * wv[k];
        C[(size_t)(m0 + r) * N3 + j] = a;
    }
}

// xp2 = seq1 @ W2 + b_in   (M=131072, N=768, K=256) tiled fp32 GEMM
__global__ __launch_bounds__(256) void gemm_xp(
    const float* __restrict__ A, const float* __restrict__ Bw,
    const float* __restrict__ bin, float* __restrict__ C) {
    __shared__ float As[16][64];
    __shared__ float Bs[16][64];
    const int tid = threadIdx.x;
    const int m0 = blockIdx.x * 64, n0 = blockIdx.y * 64;
    const int tm = (tid & 15) * 4;
    const int tn = (tid >> 4) * 4;
    float acc[4][4] = {};
    const int lm = tid >> 2, lk = (tid & 3) * 4;
    const int lkb = tid >> 4, ln = (tid & 15) * 4;
    for (int k0 = 0; k0 < 256; k0 += 16) {
        float4 av = *(const float4*)&A[(size_t)(m0 + lm) * 256 + k0 + lk];
        float4 bv = *(const float4*)&Bw[(size_t)(k0 + lkb) * N3 + n0 + ln];
        As[lk + 0][lm] = av.x; As[lk + 1][lm] = av.y;
        As[lk + 2][lm] = av.z; As[lk + 3][lm] = av.w;
        *(float4*)&Bs[lkb][ln] = bv;
        __syncthreads();
#pragma unroll
        for (int kk = 0; kk < 16; kk++) {
            float4 a = *(const float4*)&As[kk][tm];
            float4 b = *(const float4*)&Bs[kk][tn];
            acc[0][0] += a.x * b.x; acc[0][1] += a.x * b.y; acc[0][2] += a.x * b.z; acc[0][3] += a.x * b.w;
            acc[1][0] += a.y * b.x; acc[1][1] += a.y * b.y; acc[1][2] += a.y * b.z; acc[1][3] += a.y * b.w;
            acc[2][0] += a.z * b.x; acc[2][1] += a.z * b.y; acc[2][2] += a.z * b.z; acc[2][3] += a.z * b.w;
            acc[3][0] += a.w * b.x; acc[3][1] += a.w * b.y; acc[3][2] += a.w * b.z; acc[3][3] += a.w * b.w;
        }
        __syncthreads();
    }
#pragma unroll
    for (int i = 0; i < 4; i++) {
        float4 o = make_float4(acc[i][0] + bin[n0 + tn + 0], acc[i][1] + bin[n0 + tn + 1],
                               acc[i][2] + bin[n0 + tn + 2], acc[i][3] + bin[n0 + tn + 3]);
        *(float4*)&C[(size_t)(m0 + tm + i) * N3 + n0 + tn] = o;
    }
}

#define MFMA6(KT)                                                              \
    {                                                                          \
        half8 av = *(const half8*)&h2s[(KT) * 32 + arow];                      \
        a0 = __builtin_amdgcn_mfma_f32_16x16x32_f16(av, ub[0 * 8 + (KT)], a0, 0, 0, 0); \
        a1 = __builtin_amdgcn_mfma_f32_16x16x32_f16(av, ub[1 * 8 + (KT)], a1, 0, 0, 0); \
        a2 = __builtin_amdgcn_mfma_f32_16x16x32_f16(av, ub[2 * 8 + (KT)], a2, 0, 0, 0); \
        a3 = __builtin_amdgcn_mfma_f32_16x16x32_f16(av, ub[3 * 8 + (KT)], a3, 0, 0, 0); \
        a4 = __builtin_amdgcn_mfma_f32_16x16x32_f16(av, ub[4 * 8 + (KT)], a4, 0, 0, 0); \
        a5 = __builtin_amdgcn_mfma_f32_16x16x32_f16(av, ub[5 * 8 + (KT)], a5, 0, 0, 0); \
    }

// GRU recurrence via MFMA. One WG (512 thr, 8 waves) per batch element.
// rec = h(1x256) @ U(256x768): 48 n-tiles x 8 k-tiles of 16x16x32 f16 MFMA;
// wave w owns n-tiles 6w..6w+5, holding their 48 B-fragments (192 regs) in
// the unified file. MFMA reads them from AGPRs natively, so the allocator's
// AGPR-homing (which cost a copy pass per step in the VALU designs of rounds
// 2-4) is now free. A-operand = h broadcast, rebuilt per step from 512 B of
// packed f16 in LDS (one ds_read_b128 per k-tile). Only D row 0 is used.
__global__ __launch_bounds__(512) __attribute__((amdgpu_waves_per_eu(2, 2)))
void gru_mfma(const uint4* __restrict__ Up, const float* __restrict__ brec,
              const float* __restrict__ xp, float* __restrict__ seq_out,
              float* __restrict__ state_out, float* __restrict__ extra_out) {
    const int b = blockIdx.x, tid = threadIdx.x;   // tid in [0,512)
    const int w = tid >> 6, lane = tid & 63;

    __shared__ __align__(16) _Float16 h2s[UU];     // packed h, 512 B
    __shared__ float pre[N3];                      // rec row, 3 KB

    // load this wave's 48 B-fragments (16 B/lane each, coalesced)
    half8 ub[48];
#pragma unroll
    for (int f = 0; f < 48; f++)
        ub[f] = __builtin_bit_cast(half8, Up[(w * 48 + f) * 64 + lane]);

    float br0 = 0.f, br1 = 0.f, br2 = 0.f;
    if (tid < UU) { br0 = brec[tid]; br1 = brec[tid + UU]; br2 = brec[tid + 2 * UU]; }

    if (tid < 128) ((unsigned*)h2s)[tid] = 0u;
    float hst = 0.f;
    __syncthreads();

    const float* __restrict__ xpb = xp + (size_t)b * TT * N3;
    float xz = 0.f, xr = 0.f, xh = 0.f;
    if (tid < UU) { xz = xpb[tid]; xr = xpb[tid + UU]; xh = xpb[tid + 2 * UU]; }

    const int arow = (lane >> 4) << 3;             // k-subgroup base: 0,8,16,24

    for (int t = 0; t < TT; t++) {
        // prefetch next step's x-projection (consumed after next S1)
        float xzn = 0.f, xrn = 0.f, xhn = 0.f;
        if (tid < UU) {
            const float* xn = xpb + (size_t)(t + 1 < TT ? t + 1 : t) * N3;
            xzn = xn[tid]; xrn = xn[tid + UU]; xhn = xn[tid + 2 * UU];
        }

        f32x4 a0 = {0.f,0.f,0.f,0.f}, a1 = {0.f,0.f,0.f,0.f}, a2 = {0.f,0.f,0.f,0.f};
        f32x4 a3 = {0.f,0.f,0.f,0.f}, a4 = {0.f,0.f,0.f,0.f}, a5 = {0.f,0.f,0.f,0.f};
        MFMA6(0) MFMA6(1) MFMA6(2) MFMA6(3) MFMA6(4) MFMA6(5) MFMA6(6) MFMA6(7)

        // D row 0 = lanes 0..15, reg 0  (C/D: col=lane&15, row=(lane>>4)*4+reg)
        if (lane < 16) {
            pre[(w * 6 + 0) * 16 + lane] = a0[0];
            pre[(w * 6 + 1) * 16 + lane] = a1[0];
            pre[(w * 6 + 2) * 16 + lane] = a2[0];
            pre[(w * 6 + 3) * 16 + lane] = a3[0];
            pre[(w * 6 + 4) * 16 + lane] = a4[0];
            pre[(w * 6 + 5) * 16 + lane] = a5[0];
        }
        __syncthreads();                           // S1: pre ready, h2s reads done

        if (tid < UU) {
            float z  = 1.f / (1.f + __expf(-(xz + pre[tid] + br0)));
            float r  = 1.f / (1.f + __expf(-(xr + pre[tid + UU] + br1)));
            float hh = xh + r * (pre[tid + 2 * UU] + br2);
            hh = hh > 0.f ? hh : 0.f;
            float hn = z * hst + (1.f - z) * hh;
            hst = hn;
            float hq = __shfl_xor(hn, 1);          // partner unit, same wave
            if ((tid & 1) == 0) {
                half2v pk; pk.x = (_Float16)hn; pk.y = (_Float16)hq;
                *(half2v*)&h2s[tid] = pk;
            }
            if (seq_out) seq_out[(size_t)b * TT * UU + (size_t)t * UU + tid] = hn;
        }
        __syncthreads();                           // S2: h2s ready for next step
        xz = xzn; xr = xrn; xh = xhn;
    }

    if (tid < UU) {
        state_out[b * UU + tid] = hst;
        if (extra_out) extra_out[b * UU + tid] = hst;
    }
}

extern "C" void kernel_launch(void* const* d_in, const int* in_sizes, int n_in,
                              void* d_out, int out_size, void* d_ws, size_t ws_size,
                              hipStream_t stream) {
    const float* x  = (const float*)d_in[0];
    const float* W1 = (const float*)d_in[1];
    const float* U1 = (const float*)d_in[2];
    const float* b1 = (const float*)d_in[3];
    const float* W2 = (const float*)d_in[4];
    const float* U2 = (const float*)d_in[5];
    const float* b2 = (const float*)d_in[6];
    float* out = (float*)d_out;

    uint4* U1p; hipGetSymbolAddress((void**)&U1p, HIP_SYMBOL(g_U1p));
    uint4* U2p; hipGetSymbolAddress((void**)&U2p, HIP_SYMBOL(g_U2p));
    float* seq1; hipGetSymbolAddress((void**)&seq1, HIP_SYMBOL(g_seq1));
    float* xp;   hipGetSymbolAddress((void**)&xp,   HIP_SYMBOL(g_xp));

    prep_upk<<<384, 256, 0, stream>>>(U1, (unsigned*)U1p);
    prep_upk<<<384, 256, 0, stream>>>(U2, (unsigned*)U2p);

    // layer 1
    gemm_k15<<<dim3(BB * TT / 8, 3), 256, 0, stream>>>(x, W1, b1, xp);
    gru_mfma<<<BB, 512, 0, stream>>>(U1p, b1 + N3, xp, seq1, out + BB * UU, nullptr);

    // layer 2
    gemm_xp<<<dim3(BB * TT / 64, N3 / 64), 256, 0, stream>>>(seq1, W2, b2, xp);
    gru_mfma<<<BB, 512, 0, stream>>>(U2p, b2 + N3, xp, nullptr, out + 2 * BB * UU, out);
}

// Round 6
// 5268.435 us; speedup vs baseline: 1.2198x; 1.1123x over previous
//
#include <hip/hip_runtime.h>

#define BB 64
#define TT 2048
#define FF 15
#define UU 256
#define N3 768

typedef _Float16 half8 __attribute__((ext_vector_type(8)));
typedef float f32x4 __attribute__((ext_vector_type(4)));

__device__ float g_seq1[BB * TT * UU];          // 134 MB
__device__ float g_xp[(size_t)BB * TT * N3];    // 402 MB (xp1 then xp2)
__device__ uint4 g_U1p[48 * 8 * 64];            // 48 n-tiles x 8 k-tiles x 64 lanes x 16B
__device__ uint4 g_U2p[48 * 8 * 64];

// Pack U (fp32 [256][768]) into per-lane MFMA B-fragments (f16).
// Fragment (nt, kt), lane l, dword d holds {U[kt*32+8*(l>>4)+2d][nt*16+(l&15)],
// U[...+2d+1][...]}. The k-mapping f(l,i)=8*(l>>4)+i is the SAME function used
// when building the A fragment from h in the gru kernel, so any symmetric
// hardware k-permutation cancels.
__global__ __launch_bounds__(256) void prep_upk(const float* __restrict__ U,
                                                unsigned* __restrict__ Up) {
    int idx = blockIdx.x * 256 + threadIdx.x;    // 0 .. 98303
    int d = idx & 3, l = (idx >> 2) & 63, kt = (idx >> 8) & 7, nt = idx >> 11;
    int row = kt * 32 + ((l >> 4) << 3) + 2 * d;
    int col = nt * 16 + (l & 15);
    unsigned short lo = __builtin_bit_cast(unsigned short, (_Float16)U[row * N3 + col]);
    unsigned short hi = __builtin_bit_cast(unsigned short, (_Float16)U[(row + 1) * N3 + col]);
    Up[idx] = (unsigned)lo | ((unsigned)hi << 16);
}

// xp1 = x @ W1 + b_in   (K=15, memory-bound)
__global__ __launch_bounds__(256) void gemm_k15(
    const float* __restrict__ x, const float* __restrict__ W1,
    const float* __restrict__ bin, float* __restrict__ C) {
    __shared__ float xr[8][FF];
    const int m0 = blockIdx.x * 8;
    const int j  = blockIdx.y * 256 + threadIdx.x;
    if (threadIdx.x < 8 * FF) {
        int r = threadIdx.x / FF, k = threadIdx.x - r * FF;
        xr[r][k] = x[(size_t)(m0 + r) * FF + k];
    }
    __syncthreads();
    float wv[FF];
#pragma unroll
    for (int k = 0; k < FF; k++) wv[k] = W1[k * N3 + j];
    const float bj = bin[j];
#pragma unroll
    for (int r = 0; r < 8; r++) {
        float a = bj;
#pragma unroll
        for (int k = 0; k < FF; k++) a += xr[r][k] * wv[k];
        C[(size_t)(m0 + r) * N3 + j] = a;
    }
}

// xp2 = seq1 @ W2 + b_in   (M=131072, N=768, K=256) tiled fp32 GEMM
__global__ __launch_bounds__(256) void gemm_xp(
    const float* __restrict__ A, const float* __restrict__ Bw,
    const float* __restrict__ bin, float* __restrict__ C) {
    __shared__ float As[16][64];
    __shared__ float Bs[16][64];
    const int tid = threadIdx.x;
    const int m0 = blockIdx.x * 64, n0 = blockIdx.y * 64;
    const int tm = (tid & 15) * 4;
    const int tn = (tid >> 4) * 4;
    float acc[4][4] = {};
    const int lm = tid >> 2, lk = (tid & 3) * 4;
    const int lkb = tid >> 4, ln = (tid & 15) * 4;
    for (int k0 = 0; k0 < 256; k0 += 16) {
        float4 av = *(const float4*)&A[(size_t)(m0 + lm) * 256 + k0 + lk];
        float4 bv = *(const float4*)&Bw[(size_t)(k0 + lkb) * N3 + n0 + ln];
        As[lk + 0][lm] = av.x; As[lk + 1][lm] = av.y;
        As[lk + 2][lm] = av.z; As[lk + 3][lm] = av.w;
        *(float4*)&Bs[lkb][ln] = bv;
        __syncthreads();
#pragma unroll
        for (int kk = 0; kk < 16; kk++) {
            float4 a = *(const float4*)&As[kk][tm];
            float4 b = *(const float4*)&Bs[kk][tn];
            acc[0][0] += a.x * b.x; acc[0][1] += a.x * b.y; acc[0][2] += a.x * b.z; acc[0][3] += a.x * b.w;
            acc[1][0] += a.y * b.x; acc[1][1] += a.y * b.y; acc[1][2] += a.y * b.z; acc[1][3] += a.y * b.w;
            acc[2][0] += a.z * b.x; acc[2][1] += a.z * b.y; acc[2][2] += a.z * b.z; acc[2][3] += a.z * b.w;
            acc[3][0] += a.w * b.x; acc[3][1] += a.w * b.y; acc[3][2] += a.w * b.z; acc[3][3] += a.w * b.w;
        }
        __syncthreads();
    }
#pragma unroll
    for (int i = 0; i < 4; i++) {
        float4 o = make_float4(acc[i][0] + bin[n0 + tn + 0], acc[i][1] + bin[n0 + tn + 1],
                               acc[i][2] + bin[n0 + tn + 2], acc[i][3] + bin[n0 + tn + 3]);
        *(float4*)&C[(size_t)(m0 + tm + i) * N3 + n0 + tn] = o;
    }
}

// GRU recurrence via MFMA, gate-local tile assignment. One WG (512 thr,
// 8 waves) per batch element. rec = h(1x256) @ U(256x768) as 48 n-tiles x
// 8 k-tiles of 16x16x32 f16 MFMA. KEY: since A is h broadcast to all 16
// rows, ALL D rows are identical -> every lane holds the result for col
// 16*nt+(lane&15) in each acc register. Wave w owns the z/r/hh tiles of
// the SAME units (z: 2w,2w+1; r: 16+2w,17+2w; hh: 32+2w,33+2w), so lane l
// has all three gate pre-activations for units 32w+(l&15) and 32w+16+(l&15)
// in its own accumulators: gate math is thread-local on ALL 8 waves, no
// pre[] LDS round-trip, ONE barrier per step (r5 had two barriers + a
// 4-wave-idle gate phase = the 1120 cyc/step gap to the 1862-cyc pipe floor).
__global__ __launch_bounds__(512) __attribute__((amdgpu_waves_per_eu(2, 2)))
void gru_mfma2(const uint4* __restrict__ Up, const float* __restrict__ brec,
               const float* __restrict__ xp, float* __restrict__ seq_out,
               float* __restrict__ state_out, float* __restrict__ extra_out) {
    const int b = blockIdx.x, tid = threadIdx.x;   // tid in [0,512)
    const int w = tid >> 6, lane = tid & 63;
    const int l15 = lane & 15;
    const int uA = 32 * w + l15;                   // this lane's unit pair
    const int uB = uA + 16;

    __shared__ __align__(16) _Float16 h2s[2][UU];  // packed h, dbuf, 1 KB

    // this wave's 48 B-fragments: chains {z0,z1,r0,r1,h0,h1} x 8 k-tiles
    const int tz = 2 * w, tr = 16 + 2 * w, th = 32 + 2 * w;
    half8 ub[48];
#pragma unroll
    for (int kt = 0; kt < 8; kt++) {
        ub[0 * 8 + kt] = __builtin_bit_cast(half8, Up[((tz + 0) * 8 + kt) * 64 + lane]);
        ub[1 * 8 + kt] = __builtin_bit_cast(half8, Up[((tz + 1) * 8 + kt) * 64 + lane]);
        ub[2 * 8 + kt] = __builtin_bit_cast(half8, Up[((tr + 0) * 8 + kt) * 64 + lane]);
        ub[3 * 8 + kt] = __builtin_bit_cast(half8, Up[((tr + 1) * 8 + kt) * 64 + lane]);
        ub[4 * 8 + kt] = __builtin_bit_cast(half8, Up[((th + 0) * 8 + kt) * 64 + lane]);
        ub[5 * 8 + kt] = __builtin_bit_cast(half8, Up[((th + 1) * 8 + kt) * 64 + lane]);
    }
    const float brzA = brec[uA], brrA = brec[uA + UU], brhA = brec[uA + 2 * UU];
    const float brzB = brec[uB], brrB = brec[uB + UU], brhB = brec[uB + 2 * UU];

    if (tid < 128) ((unsigned*)h2s[0])[tid] = 0u;  // zero h(0)
    float hA = 0.f, hB = 0.f;                      // fp32 h state, in-register
    __syncthreads();

    const float* __restrict__ xpb = xp + (size_t)b * TT * N3;
    float xzA = xpb[uA], xrA = xpb[uA + UU], xhA = xpb[uA + 2 * UU];
    float xzB = xpb[uB], xrB = xpb[uB + UU], xhB = xpb[uB + 2 * UU];

    const int arow = (lane >> 4) << 3;             // k-subgroup base: 0,8,16,24

    for (int t = 0; t < TT; t++) {
        // prefetch next step's x-projection (~1800 cyc of latency headroom)
        const float* xn = xpb + (size_t)(t + 1 < TT ? t + 1 : t) * N3;
        float xzAn = xn[uA], xrAn = xn[uA + UU], xhAn = xn[uA + 2 * UU];
        float xzBn = xn[uB], xrBn = xn[uB + UU], xhBn = xn[uB + 2 * UU];

        const _Float16* hcur = h2s[t & 1];
        f32x4 a0 = {0.f, 0.f, 0.f, 0.f}, a1 = a0, a2 = a0, a3 = a0, a4 = a0, a5 = a0;
#pragma unroll
        for (int kt = 0; kt < 8; kt++) {
            half8 av = *(const half8*)&hcur[kt * 32 + arow];
            a0 = __builtin_amdgcn_mfma_f32_16x16x32_f16(av, ub[0 * 8 + kt], a0, 0, 0, 0);
            a1 = __builtin_amdgcn_mfma_f32_16x16x32_f16(av, ub[1 * 8 + kt], a1, 0, 0, 0);
            a2 = __builtin_amdgcn_mfma_f32_16x16x32_f16(av, ub[2 * 8 + kt], a2, 0, 0, 0);
            a3 = __builtin_amdgcn_mfma_f32_16x16x32_f16(av, ub[3 * 8 + kt], a3, 0, 0, 0);
            a4 = __builtin_amdgcn_mfma_f32_16x16x32_f16(av, ub[4 * 8 + kt], a4, 0, 0, 0);
            a5 = __builtin_amdgcn_mfma_f32_16x16x32_f16(av, ub[5 * 8 + kt], a5, 0, 0, 0);
        }

        // gates, fully thread-local (acc reg 0 holds col l15 of each tile)
        float zA = 1.f / (1.f + __expf(-(xzA + a0[0] + brzA)));
        float zB = 1.f / (1.f + __expf(-(xzB + a1[0] + brzB)));
        float rA = 1.f / (1.f + __expf(-(xrA + a2[0] + brrA)));
        float rB = 1.f / (1.f + __expf(-(xrB + a3[0] + brrB)));
        float hhA = xhA + rA * (a4[0] + brhA); hhA = hhA > 0.f ? hhA : 0.f;
        float hhB = xhB + rB * (a5[0] + brhB); hhB = hhB > 0.f ? hhB : 0.f;
        hA = zA * hA + (1.f - zA) * hhA;
        hB = zB * hB + (1.f - zB) * hhB;

        // publish h (lanes 0-15: uA, lanes 16-31: uB; quarters 2,3 redundant)
        _Float16* hnxt = h2s[(t + 1) & 1];
        if (lane < 32) {
            int   u  = (lane < 16) ? uA : uB;
            float hv = (lane < 16) ? hA : hB;
            hnxt[u] = (_Float16)hv;
            if (seq_out)
                seq_out[(size_t)b * TT * UU + (size_t)t * UU + u] = hv;
        }
        __syncthreads();                           // single barrier per step
        xzA = xzAn; xrA = xrAn; xhA = xhAn;
        xzB = xzBn; xrB = xrBn; xhB = xhBn;
    }

    if (lane < 32) {
        int   u  = (lane < 16) ? uA : uB;
        float hv = (lane < 16) ? hA : hB;
        state_out[b * UU + u] = hv;
        if (extra_out) extra_out[b * UU + u] = hv;
    }
}

extern "C" void kernel_launch(void* const* d_in, const int* in_sizes, int n_in,
                              void* d_out, int out_size, void* d_ws, size_t ws_size,
                              hipStream_t stream) {
    const float* x  = (const float*)d_in[0];
    const float* W1 = (const float*)d_in[1];
    const float* U1 = (const float*)d_in[2];
    const float* b1 = (const float*)d_in[3];
    const float* W2 = (const float*)d_in[4];
    const float* U2 = (const float*)d_in[5];
    const float* b2 = (const float*)d_in[6];
    float* out = (float*)d_out;

    uint4* U1p; hipGetSymbolAddress((void**)&U1p, HIP_SYMBOL(g_U1p));
    uint4* U2p; hipGetSymbolAddress((void**)&U2p, HIP_SYMBOL(g_U2p));
    float* seq1; hipGetSymbolAddress((void**)&seq1, HIP_SYMBOL(g_seq1));
    float* xp;   hipGetSymbolAddress((void**)&xp,   HIP_SYMBOL(g_xp));

    prep_upk<<<384, 256, 0, stream>>>(U1, (unsigned*)U1p);
    prep_upk<<<384, 256, 0, stream>>>(U2, (unsigned*)U2p);

    // layer 1
    gemm_k15<<<dim3(BB * TT / 8, 3), 256, 0, stream>>>(x, W1, b1, xp);
    gru_mfma2<<<BB, 512, 0, stream>>>(U1p, b1 + N3, xp, seq1, out + BB * UU, nullptr);

    // layer 2
    gemm_xp<<<dim3(BB * TT / 64, N3 / 64), 256, 0, stream>>>(seq1, W2, b2, xp);
    gru_mfma2<<<BB, 512, 0, stream>>>(U2p, b2 + N3, xp, nullptr, out + 2 * BB * UU, out);
}

// Round 9
// 5026.127 us; speedup vs baseline: 1.2786x; 1.0482x over previous
//
#include <hip/hip_runtime.h>

#define BB 64
#define TT 2048
#define FF 15
#define UU 256
#define N3 768

typedef _Float16 half8 __attribute__((ext_vector_type(8)));
typedef float f32x4 __attribute__((ext_vector_type(4)));

__device__ float g_seq1[BB * TT * UU];          // 134 MB
__device__ float g_xp[(size_t)BB * TT * N3];    // 402 MB (xp1 then xp2)
__device__ uint4 g_U1p[48 * 8 * 64];            // 48 n-tiles x 8 k-tiles x 64 lanes x 16B
__device__ uint4 g_U2p[48 * 8 * 64];
__device__ uint4 g_W2p[48 * 8 * 64];            // W2 in the same fragment layout

// Pack a 256x768 fp32 matrix into per-lane MFMA B-fragments (f16).
// Fragment (nt, kt), lane l, dword d holds {M[kt*32+8*(l>>4)+2d][nt*16+(l&15)],
// M[...+2d+1][...]}. k-mapping f(l,i)=8*(l>>4)+i matches the A-side builds.
__global__ __launch_bounds__(256) void prep_upk(const float* __restrict__ U,
                                                unsigned* __restrict__ Up) {
    int idx = blockIdx.x * 256 + threadIdx.x;    // 0 .. 98303
    int d = idx & 3, l = (idx >> 2) & 63, kt = (idx >> 8) & 7, nt = idx >> 11;
    int row = kt * 32 + ((l >> 4) << 3) + 2 * d;
    int col = nt * 16 + (l & 15);
    unsigned short lo = __builtin_bit_cast(unsigned short, (_Float16)U[row * N3 + col]);
    unsigned short hi = __builtin_bit_cast(unsigned short, (_Float16)U[(row + 1) * N3 + col]);
    Up[idx] = (unsigned)lo | ((unsigned)hi << 16);
}

// xp1 = x @ W1 + b_in   (K=15, memory-bound)
__global__ __launch_bounds__(256) void gemm_k15(
    const float* __restrict__ x, const float* __restrict__ W1,
    const float* __restrict__ bin, float* __restrict__ C) {
    __shared__ float xr[8][FF];
    const int m0 = blockIdx.x * 8;
    const int j  = blockIdx.y * 256 + threadIdx.x;
    if (threadIdx.x < 8 * FF) {
        int r = threadIdx.x / FF, k = threadIdx.x - r * FF;
        xr[r][k] = x[(size_t)(m0 + r) * FF + k];
    }
    __syncthreads();
    float wv[FF];
#pragma unroll
    for (int k = 0; k < FF; k++) wv[k] = W1[k * N3 + j];
    const float bj = bin[j];
#pragma unroll
    for (int r = 0; r < 8; r++) {
        float a = bj;
#pragma unroll
        for (int k = 0; k < FF; k++) a += xr[r][k] * wv[k];
        C[(size_t)(m0 + r) * N3 + j] = a;
    }
}

// xp2 = seq1 @ W2 + b_in  via f16 MFMA. M=131072, N=768, K=256.
// Block = 64 rows x full N. 8 waves: wave w -> M-tile (w>>1), n-tiles
// 24*(w&1)..+23. A-fragments read straight from f32 seq1 (row = lane&15,
// k = kt*32 + 8*(lane>>4)+i -- the documented dual of the B mapping that
// r5/r6 validated); B-fragments streamed from the L2-resident packed W2
// (393 KB). acc = 24 f32x4 = 96 VGPRs, static indices only -> arch VGPRs.
__global__ __launch_bounds__(512) void gemm_xp_mfma(
    const float* __restrict__ A, const uint4* __restrict__ Wp,
    const float* __restrict__ bin, float* __restrict__ C) {
    const int tid = threadIdx.x, w = tid >> 6, lane = tid & 63;
    const int mt = w >> 1;                       // 0..3
    const int nb = (w & 1) * 24;                 // n-tile base
    const int arow = blockIdx.x * 64 + mt * 16 + (lane & 15);
    const int ko   = (lane >> 4) * 8;

    f32x4 acc[24] = {};
    const float* ap = A + (size_t)arow * 256 + ko;

#pragma unroll
    for (int kt = 0; kt < 8; kt++) {
        float4 p0 = *(const float4*)(ap + kt * 32);
        float4 p1 = *(const float4*)(ap + kt * 32 + 4);
        half8 av;
        av[0] = (_Float16)p0.x; av[1] = (_Float16)p0.y;
        av[2] = (_Float16)p0.z; av[3] = (_Float16)p0.w;
        av[4] = (_Float16)p1.x; av[5] = (_Float16)p1.y;
        av[6] = (_Float16)p1.z; av[7] = (_Float16)p1.w;
        const uint4* wp = Wp + (size_t)(nb * 8 + kt) * 64 + lane;
#pragma unroll
        for (int n = 0; n < 24; n++) {
            half8 bf = __builtin_bit_cast(half8, wp[(size_t)n * 8 * 64]);
            acc[n] = __builtin_amdgcn_mfma_f32_16x16x32_f16(av, bf, acc[n], 0, 0, 0);
        }
    }
    // D: col = lane&15, row-in-tile = (lane>>4)*4 + reg   (m89-verified)
    const int rbase = blockIdx.x * 64 + mt * 16 + (lane >> 4) * 4;
#pragma unroll
    for (int n = 0; n < 24; n++) {
        int col = (nb + n) * 16 + (lane & 15);
        float bv = bin[col];
#pragma unroll
        for (int d = 0; d < 4; d++)
            C[(size_t)(rbase + d) * N3 + col] = acc[n][d] + bv;
    }
}

// ---------------- GRU recurrence: r6-validated intrinsic version -------------
// One WG (512 thr, 8 waves) per batch element. rec = h(1x256) @ U(256x768) as
// 48 n-tiles x 8 k-tiles of 16x16x32 f16 MFMA. A = h broadcast to all 16 rows
// -> all D rows identical -> every lane holds col 16*nt+(lane&15) in acc reg 0.
// Wave w owns the z/r/hh tiles of units 32w..32w+31, so gate math is
// thread-local on all 8 waves; one barrier per step.
__global__ __launch_bounds__(512) __attribute__((amdgpu_waves_per_eu(2, 2)))
void gru_mfma2(const uint4* __restrict__ Up, const float* __restrict__ brec,
               const float* __restrict__ xp, float* __restrict__ seq_out,
               float* __restrict__ state_out, float* __restrict__ extra_out) {
    const int b = blockIdx.x, tid = threadIdx.x;
    const int w = tid >> 6, lane = tid & 63;
    const int l15 = lane & 15;
    const int uA = 32 * w + l15, uB = uA + 16;

    __shared__ __align__(16) _Float16 h2s[2][UU];

    const int tz = 2 * w, tr = 16 + 2 * w, th = 32 + 2 * w;
    half8 ub[48];
#pragma unroll
    for (int kt = 0; kt < 8; kt++) {
        ub[0 * 8 + kt] = __builtin_bit_cast(half8, Up[((tz + 0) * 8 + kt) * 64 + lane]);
        ub[1 * 8 + kt] = __builtin_bit_cast(half8, Up[((tz + 1) * 8 + kt) * 64 + lane]);
        ub[2 * 8 + kt] = __builtin_bit_cast(half8, Up[((tr + 0) * 8 + kt) * 64 + lane]);
        ub[3 * 8 + kt] = __builtin_bit_cast(half8, Up[((tr + 1) * 8 + kt) * 64 + lane]);
        ub[4 * 8 + kt] = __builtin_bit_cast(half8, Up[((th + 0) * 8 + kt) * 64 + lane]);
        ub[5 * 8 + kt] = __builtin_bit_cast(half8, Up[((th + 1) * 8 + kt) * 64 + lane]);
    }
    const float brzA = brec[uA], brrA = brec[uA + UU], brhA = brec[uA + 2 * UU];
    const float brzB = brec[uB], brrB = brec[uB + UU], brhB = brec[uB + 2 * UU];

    if (tid < 128) ((unsigned*)h2s[0])[tid] = 0u;
    float hA = 0.f, hB = 0.f;
    __syncthreads();

    const float* __restrict__ xpb = xp + (size_t)b * TT * N3;
    float xzA = xpb[uA], xrA = xpb[uA + UU], xhA = xpb[uA + 2 * UU];
    float xzB = xpb[uB], xrB = xpb[uB + UU], xhB = xpb[uB + 2 * UU];

    const int arow = (lane >> 4) << 3;

    for (int t = 0; t < TT; t++) {
        const float* xn = xpb + (size_t)(t + 1 < TT ? t + 1 : t) * N3;
        float xzAn = xn[uA], xrAn = xn[uA + UU], xhAn = xn[uA + 2 * UU];
        float xzBn = xn[uB], xrBn = xn[uB + UU], xhBn = xn[uB + 2 * UU];

        const _Float16* hcur = h2s[t & 1];
        f32x4 a0 = {0.f, 0.f, 0.f, 0.f}, a1 = a0, a2 = a0, a3 = a0, a4 = a0, a5 = a0;
#pragma unroll
        for (int kt = 0; kt < 8; kt++) {
            half8 av = *(const half8*)&hcur[kt * 32 + arow];
            a0 = __builtin_amdgcn_mfma_f32_16x16x32_f16(av, ub[0 * 8 + kt], a0, 0, 0, 0);
            a1 = __builtin_amdgcn_mfma_f32_16x16x32_f16(av, ub[1 * 8 + kt], a1, 0, 0, 0);
            a2 = __builtin_amdgcn_mfma_f32_16x16x32_f16(av, ub[2 * 8 + kt], a2, 0, 0, 0);
            a3 = __builtin_amdgcn_mfma_f32_16x16x32_f16(av, ub[3 * 8 + kt], a3, 0, 0, 0);
            a4 = __builtin_amdgcn_mfma_f32_16x16x32_f16(av, ub[4 * 8 + kt], a4, 0, 0, 0);
            a5 = __builtin_amdgcn_mfma_f32_16x16x32_f16(av, ub[5 * 8 + kt], a5, 0, 0, 0);
        }

        float zA = 1.f / (1.f + __expf(-(xzA + a0[0] + brzA)));
        float zB = 1.f / (1.f + __expf(-(xzB + a1[0] + brzB)));
        float rA = 1.f / (1.f + __expf(-(xrA + a2[0] + brrA)));
        float rB = 1.f / (1.f + __expf(-(xrB + a3[0] + brrB)));
        float hhA = xhA + rA * (a4[0] + brhA); hhA = hhA > 0.f ? hhA : 0.f;
        float hhB = xhB + rB * (a5[0] + brhB); hhB = hhB > 0.f ? hhB : 0.f;
        hA = zA * hA + (1.f - zA) * hhA;
        hB = zB * hB + (1.f - zB) * hhB;

        _Float16* hnxt = h2s[(t + 1) & 1];
        if (lane < 32) {
            int   u  = (lane < 16) ? uA : uB;
            float hv = (lane < 16) ? hA : hB;
            hnxt[u] = (_Float16)hv;
            if (seq_out)
                seq_out[(size_t)b * TT * UU + (size_t)t * UU + u] = hv;
        }
        __syncthreads();
        xzA = xzAn; xrA = xrAn; xhA = xhAn;
        xzB = xzBn; xrB = xrBn; xhB = xhBn;
    }

    if (lane < 32) {
        int   u  = (lane < 16) ? uA : uB;
        float hv = (lane < 16) ? hA : hB;
        state_out[b * UU + u] = hv;
        if (extra_out) extra_out[b * UU + u] = hv;
    }
}

extern "C" void kernel_launch(void* const* d_in, const int* in_sizes, int n_in,
                              void* d_out, int out_size, void* d_ws, size_t ws_size,
                              hipStream_t stream) {
    const float* x  = (const float*)d_in[0];
    const float* W1 = (const float*)d_in[1];
    const float* U1 = (const float*)d_in[2];
    const float* b1 = (const float*)d_in[3];
    const float* W2 = (const float*)d_in[4];
    const float* U2 = (const float*)d_in[5];
    const float* b2 = (const float*)d_in[6];
    float* out = (float*)d_out;

    uint4* U1p; hipGetSymbolAddress((void**)&U1p, HIP_SYMBOL(g_U1p));
    uint4* U2p; hipGetSymbolAddress((void**)&U2p, HIP_SYMBOL(g_U2p));
    uint4* W2p; hipGetSymbolAddress((void**)&W2p, HIP_SYMBOL(g_W2p));
    float* seq1; hipGetSymbolAddress((void**)&seq1, HIP_SYMBOL(g_seq1));
    float* xp;   hipGetSymbolAddress((void**)&xp,   HIP_SYMBOL(g_xp));

    prep_upk<<<384, 256, 0, stream>>>(U1, (unsigned*)U1p);
    prep_upk<<<384, 256, 0, stream>>>(U2, (unsigned*)U2p);
    prep_upk<<<384, 256, 0, stream>>>(W2, (unsigned*)W2p);

    // layer 1 (validated gru)
    gemm_k15<<<dim3(BB * TT / 8, 3), 256, 0, stream>>>(x, W1, b1, xp);
    gru_mfma2<<<BB, 512, 0, stream>>>(U1p, b1 + N3, xp, seq1, out + BB * UU, nullptr);

    // layer 2: NEW isolated component -> MFMA xp2 GEMM; validated gru
    gemm_xp_mfma<<<BB * TT / 64, 512, 0, stream>>>(seq1, W2p, b2, xp);
    gru_mfma2<<<BB, 512, 0, stream>>>(U2p, b2 + N3, xp, nullptr, out + 2 * BB * UU, out);
}